// Round 1
// baseline (794.730 us; speedup 1.0000x reference)
//
#include <hip/hip_runtime.h>
#include <math.h>

typedef __attribute__((ext_vector_type(8))) short short8;
typedef __attribute__((ext_vector_type(4))) float f32x4;
typedef short bf16s;   // bf16 stored as raw 16-bit

#define NL 4
#define NB 4
#define SS 512
#define DD 512
#define NH 8
#define S2 1024
#define ROWS 2048   // NB*SS

static __device__ __forceinline__ float bfs2f(short s) {
    union { unsigned u; float f; } c; c.u = ((unsigned)(unsigned short)s) << 16; return c.f;
}
static __device__ __forceinline__ short f2bfs(float f) {
    union { float f; unsigned u; } c; c.f = f;
    unsigned r = 0x7FFFu + ((c.u >> 16) & 1u);
    return (short)((c.u + r) >> 16);
}

// ---------------- prep kernels ----------------

__global__ void pos_kernel(float* __restrict__ posf, bf16s* __restrict__ posb)
{
    const int t = blockIdx.x, f = threadIdx.x;       // 1024 x 32
    float freq = expf((float)f * (-9.210340371976184f / 31.0f));
    float ang  = (float)(t - 512) * freq;
    float sv = sinf(ang), cv = cosf(ang);
    posf[t*64 + f]      = sv;  posf[t*64 + 32 + f] = cv;
    posb[t*64 + f]      = f2bfs(sv);
    posb[t*64 + 32 + f] = f2bfs(cv);
}

__global__ void dtab_kernel(const float* __restrict__ rw, const float* __restrict__ posf,
                            float* __restrict__ dt)
{
    int idx = blockIdx.x*256 + threadIdx.x;          // < NL*NH*1024 = 32768
    int j = idx & 1023, hh = (idx >> 10) & 7, l = idx >> 13;
    const float* rv = rw + (l*NH + hh)*64;
    const float* pv = posf + j*64;
    float s = 0.f;
    #pragma unroll 8
    for (int d = 0; d < 64; ++d) s += rv[d]*pv[d];
    dt[idx] = s;
}

__global__ __launch_bounds__(256) void transpose_cvt(const float* __restrict__ in,
                                                     bf16s* __restrict__ out, int R, int C)
{
    __shared__ float tile[32][33];
    const int bx = blockIdx.x*32, by = blockIdx.y*32;
    const size_t zoff = (size_t)blockIdx.z * R * C;
    in += zoff; out += zoff;
    const int tx = threadIdx.x & 31, ty = threadIdx.x >> 5;
    for (int i = ty; i < 32; i += 8) tile[i][tx] = in[(size_t)(by+i)*C + bx+tx];
    __syncthreads();
    for (int i = ty; i < 32; i += 8) out[(size_t)(bx+i)*R + by+tx] = f2bfs(tile[tx][i]);
}

__global__ void cvt_f2b(const float* __restrict__ in, bf16s* __restrict__ out, int n)
{
    int i = (blockIdx.x*blockDim.x + threadIdx.x)*4;
    if (i >= n) return;
    float4 v = *(const float4*)(in + i);
    out[i]   = f2bfs(v.x); out[i+1] = f2bfs(v.y);
    out[i+2] = f2bfs(v.z); out[i+3] = f2bfs(v.w);
}

// ---------------- generic BT-layout bf16 MFMA GEMM ----------------
// A [M][K] bf16 (lda), B [N][K] bf16 (ldb), C [M][N]
// MODE 0: plain.  MODE 1: T23 batched (z = (b*8+h)*2+t, A from qkv).  MODE 2: PV batched.
// EPI 0: f32.  1: bf16.  2: +bias,gelu -> bf16.  3: +bias -> f32.  4: (+Dtab if t==0) -> bf16.
template<int MODE, int EPI>
__global__ __launch_bounds__(256) void gemm_bt(
    const bf16s* __restrict__ Abase, const bf16s* __restrict__ Bbase,
    void* __restrict__ Cbase, const float* __restrict__ bias,
    const float* __restrict__ Dtab,
    int M, int N, int K, int lda, int ldb, int ldc)
{
    const int z = blockIdx.z;
    const bf16s* A = Abase;
    const bf16s* Bp = Bbase;
    float* Cf = (float*)Cbase;
    bf16s* Cb = (bf16s*)Cbase;
    int hIdx = 0, tIdx = 0;
    if constexpr (MODE == 1) {
        int bh = z >> 1; tIdx = z & 1;
        int b_ = bh >> 3; hIdx = bh & 7;
        A  = Abase + (size_t)b_*SS*1536 + hIdx*64 + tIdx*512;
        Cb = (bf16s*)Cbase + (size_t)z*SS*S2;
    } else if constexpr (MODE == 2) {
        A  = Abase + (size_t)z*SS*SS;
        Bp = Bbase + (size_t)z*64*SS;
        Cf = (float*)Cbase + (size_t)(z>>3)*SS*DD + (size_t)(z&7)*64;
    }
    const int w = threadIdx.x >> 6, lane = threadIdx.x & 63;
    const int lr = lane & 15, lg = lane >> 4;
    const int m0 = blockIdx.x*64 + (w>>1)*32;
    const int n0 = blockIdx.y*64 + (w&1)*32;
    const int koff = lg*8;
    const bf16s* Arow0 = A + (size_t)(m0 + lr)*lda + koff;
    const bf16s* Arow1 = Arow0 + (size_t)16*lda;
    const bf16s* Brow0 = Bp + (size_t)(n0 + lr)*ldb + koff;
    const bf16s* Brow1 = Brow0 + (size_t)16*ldb;
    f32x4 acc00 = {0,0,0,0}, acc01 = {0,0,0,0}, acc10 = {0,0,0,0}, acc11 = {0,0,0,0};
    for (int k0 = 0; k0 < K; k0 += 32) {
        short8 a0 = *(const short8*)(Arow0 + k0);
        short8 a1 = *(const short8*)(Arow1 + k0);
        short8 b0 = *(const short8*)(Brow0 + k0);
        short8 b1 = *(const short8*)(Brow1 + k0);
        acc00 = __builtin_amdgcn_mfma_f32_16x16x32_bf16(a0, b0, acc00, 0,0,0);
        acc01 = __builtin_amdgcn_mfma_f32_16x16x32_bf16(a0, b1, acc01, 0,0,0);
        acc10 = __builtin_amdgcn_mfma_f32_16x16x32_bf16(a1, b0, acc10, 0,0,0);
        acc11 = __builtin_amdgcn_mfma_f32_16x16x32_bf16(a1, b1, acc11, 0,0,0);
    }
    f32x4 accs[2][2] = {{acc00, acc01},{acc10, acc11}};
    #pragma unroll
    for (int mi = 0; mi < 2; ++mi)
    #pragma unroll
    for (int ni = 0; ni < 2; ++ni) {
        int r0 = m0 + mi*16 + lg*4;
        int c  = n0 + ni*16 + lr;
        #pragma unroll
        for (int q = 0; q < 4; ++q) {
            float val = accs[mi][ni][q];
            if constexpr (EPI == 2 || EPI == 3) val += bias[c];
            if constexpr (EPI == 2) val = 0.5f*val*(1.0f + erff(val*0.70710678118f));
            if constexpr (EPI == 4) { if (tIdx == 0) val += Dtab[hIdx*S2 + c]; }
            size_t idx = (size_t)(r0+q)*ldc + c;
            if constexpr (EPI == 0 || EPI == 3) Cf[idx] = val;
            else Cb[idx] = f2bfs(val);
        }
    }
}

// ---------------- V transpose (qkv v-part -> Vt[b][h][d][s]) ----------------
__global__ __launch_bounds__(256) void transpose_v(const bf16s* __restrict__ qkv,
                                                   bf16s* __restrict__ vt)
{
    __shared__ bf16s tile[64][65];
    const int st = blockIdx.x*64, h = blockIdx.y, b = blockIdx.z;
    const int r = threadIdx.x >> 2, cq = (threadIdx.x & 3)*16;
    const bf16s* src = qkv + (size_t)(b*SS + st + r)*1536 + 1024 + h*64 + cq;
    #pragma unroll
    for (int j = 0; j < 16; ++j) tile[r][cq + j] = src[j];
    __syncthreads();
    bf16s* dst = vt + (size_t)((b*NH + h)*64 + r)*SS + st + cq;
    #pragma unroll
    for (int j = 0; j < 16; ++j) dst[j] = tile[cq + j][r];
}

// ---------------- fused scores + rel-pos gather + softmax -> P (bf16) ----------------
// score[i,k] = (q_i+rr)·k_k + T2[i, 512+k-i] + T3[k, 512+i-k]   (T2 includes Dtab)
__global__ __launch_bounds__(256) void scores_kernel(
    const bf16s* __restrict__ qkv, const bf16s* __restrict__ T23,
    const float* __restrict__ rr, bf16s* __restrict__ P)
{
    const int it = blockIdx.x, h = blockIdx.y, b = blockIdx.z;
    const int w = threadIdx.x >> 6, lane = threadIdx.x & 63;
    const int lr = lane & 15, lg = lane >> 4, koff = lg*8;
    const int i0 = it*64 + w*16;

    short8 aq[2];
    #pragma unroll
    for (int kk = 0; kk < 2; ++kk) {
        const bf16s* pq = qkv + (size_t)(b*SS + i0 + lr)*1536 + h*64 + kk*32 + koff;
        short8 raw = *(const short8*)pq;
        #pragma unroll
        for (int j = 0; j < 8; ++j) {
            float f = bfs2f(raw[j]) + rr[h*64 + kk*32 + koff + j];
            raw[j] = f2bfs(f);
        }
        aq[kk] = raw;
    }

    f32x4 acc[32];
    #pragma unroll
    for (int f = 0; f < 32; ++f) acc[f] = (f32x4){0,0,0,0};
    #pragma unroll
    for (int f = 0; f < 32; ++f) {
        const bf16s* pk = qkv + (size_t)(b*SS + f*16 + lr)*1536 + 512 + h*64 + koff;
        short8 b0 = *(const short8*)pk;
        short8 b1 = *(const short8*)(pk + 32);
        acc[f] = __builtin_amdgcn_mfma_f32_16x16x32_bf16(aq[0], b0, acc[f], 0,0,0);
        acc[f] = __builtin_amdgcn_mfma_f32_16x16x32_bf16(aq[1], b1, acc[f], 0,0,0);
    }

    const bf16s* T2 = T23 + (size_t)((b*NH + h)*2)*SS*S2;
    const bf16s* T3 = T2 + (size_t)SS*S2;
    #pragma unroll
    for (int f = 0; f < 32; ++f) {
        int c = f*16 + lr;
        #pragma unroll
        for (int q = 0; q < 4; ++q) {
            int r = i0 + lg*4 + q;
            float v = acc[f][q];
            v += bfs2f(T2[(size_t)r*S2 + (512 + c - r)]);
            v += bfs2f(T3[(size_t)c*S2 + (512 + r - c)]);
            acc[f][q] = v * 0.125f;   // / sqrt(64)
        }
    }

    float mx[4] = {-3e38f,-3e38f,-3e38f,-3e38f};
    #pragma unroll
    for (int f = 0; f < 32; ++f)
        #pragma unroll
        for (int q = 0; q < 4; ++q) mx[q] = fmaxf(mx[q], acc[f][q]);
    #pragma unroll
    for (int d = 1; d < 16; d <<= 1)
        #pragma unroll
        for (int q = 0; q < 4; ++q) mx[q] = fmaxf(mx[q], __shfl_xor(mx[q], d));

    float sm[4] = {0,0,0,0};
    #pragma unroll
    for (int f = 0; f < 32; ++f)
        #pragma unroll
        for (int q = 0; q < 4; ++q) {
            float pv = expf(acc[f][q] - mx[q]);
            acc[f][q] = pv; sm[q] += pv;
        }
    #pragma unroll
    for (int d = 1; d < 16; d <<= 1)
        #pragma unroll
        for (int q = 0; q < 4; ++q) sm[q] += __shfl_xor(sm[q], d);
    float inv[4];
    #pragma unroll
    for (int q = 0; q < 4; ++q) inv[q] = 1.0f / sm[q];

    bf16s* Pb = P + (size_t)(b*NH + h)*SS*SS;
    #pragma unroll
    for (int f = 0; f < 32; ++f)
        #pragma unroll
        for (int q = 0; q < 4; ++q)
            Pb[(size_t)(i0 + lg*4 + q)*SS + f*16 + lr] = f2bfs(acc[f][q]*inv[q]);
}

// ---------------- layernorm (a + res), writes f32 + bf16 ----------------
__global__ __launch_bounds__(64) void ln_kernel(
    const float* __restrict__ a, const float* __restrict__ res,
    const float* __restrict__ g, const float* __restrict__ be,
    float* __restrict__ outf, bf16s* __restrict__ outb)
{
    const int row = blockIdx.x, lane = threadIdx.x;
    const float4* pa = (const float4*)(a   + (size_t)row*DD) + lane*2;
    const float4* pr = (const float4*)(res + (size_t)row*DD) + lane*2;
    float4 a0 = pa[0], a1 = pa[1], r0 = pr[0], r1 = pr[1];
    float xv[8] = {a0.x+r0.x, a0.y+r0.y, a0.z+r0.z, a0.w+r0.w,
                   a1.x+r1.x, a1.y+r1.y, a1.z+r1.z, a1.w+r1.w};
    float s = 0.f;
    #pragma unroll
    for (int j = 0; j < 8; ++j) s += xv[j];
    #pragma unroll
    for (int d = 1; d < 64; d <<= 1) s += __shfl_xor(s, d);
    float mean = s * (1.0f/512.0f);
    float v = 0.f;
    #pragma unroll
    for (int j = 0; j < 8; ++j) { float t = xv[j]-mean; v += t*t; }
    #pragma unroll
    for (int d = 1; d < 64; d <<= 1) v += __shfl_xor(v, d);
    float rstd = rsqrtf(v*(1.0f/512.0f) + 1e-5f);
    const int c0 = lane*8;
    short8 ob;
    #pragma unroll
    for (int j = 0; j < 8; ++j) {
        float o = (xv[j]-mean)*rstd*g[c0+j] + be[c0+j];
        outf[(size_t)row*DD + c0 + j] = o;
        ob[j] = f2bfs(o);
    }
    *(short8*)(outb + (size_t)row*DD + c0) = ob;
}

// ---------------- host ----------------
extern "C" void kernel_launch(void* const* d_in, const int* in_sizes, int n_in,
                              void* d_out, int out_size, void* d_ws, size_t ws_size,
                              hipStream_t stream)
{
    const float* x    = (const float*)d_in[0];
    const float* Wqkv = (const float*)d_in[1];
    const float* r_r  = (const float*)d_in[2];
    const float* r_w  = (const float*)d_in[3];
    const float* ln1g = (const float*)d_in[4];
    const float* ln1b = (const float*)d_in[5];
    const float* w1   = (const float*)d_in[6];
    const float* b1   = (const float*)d_in[7];
    const float* w2   = (const float*)d_in[8];
    const float* b2   = (const float*)d_in[9];
    const float* ln2g = (const float*)d_in[10];
    const float* ln2b = (const float*)d_in[11];

    char* p = (char*)d_ws;
    auto alloc = [&](size_t bytes) { char* r = p; p += (bytes + 255) & ~(size_t)255; return r; };
    float* posf  = (float*)alloc((size_t)1024*64*4);
    bf16s* posb  = (bf16s*)alloc((size_t)1024*64*2);
    float* dtab  = (float*)alloc((size_t)NL*NH*1024*4);
    bf16s* wqkvT = (bf16s*)alloc((size_t)NL*1536*512*2);
    bf16s* w1T   = (bf16s*)alloc((size_t)NL*512*512*2);
    bf16s* w2T   = (bf16s*)alloc((size_t)NL*512*512*2);
    float* hbuf  = (float*)alloc((size_t)ROWS*512*4);
    bf16s* hbf   = (bf16s*)alloc((size_t)ROWS*512*2);
    bf16s* qkvb  = (bf16s*)alloc((size_t)ROWS*1536*2);
    bf16s* vt    = (bf16s*)alloc((size_t)32*64*512*2);
    bf16s* t23   = (bf16s*)alloc((size_t)64*512*1024*2);
    bf16s* pmat  = (bf16s*)alloc((size_t)32*512*512*2);
    float* obuf  = (float*)alloc((size_t)ROWS*512*4);
    float* h1    = (float*)alloc((size_t)ROWS*512*4);
    bf16s* h1bf  = (bf16s*)alloc((size_t)ROWS*512*2);
    bf16s* f1bf  = (bf16s*)alloc((size_t)ROWS*512*2);
    float* f2    = (float*)alloc((size_t)ROWS*512*4);

    pos_kernel<<<1024, 32, 0, stream>>>(posf, posb);
    dtab_kernel<<<128, 256, 0, stream>>>(r_w, posf, dtab);
    transpose_cvt<<<dim3(48,16,NL), 256, 0, stream>>>(Wqkv, wqkvT, 512, 1536);
    transpose_cvt<<<dim3(16,16,NL), 256, 0, stream>>>(w1, w1T, 512, 512);
    transpose_cvt<<<dim3(16,16,NL), 256, 0, stream>>>(w2, w2T, 512, 512);
    cvt_f2b<<<1024, 256, 0, stream>>>(x, hbf, ROWS*512);

    for (int l = 0; l < NL; ++l) {
        // qkv = h @ Wqkv   (bf16 out)
        gemm_bt<0,1><<<dim3(32,24,1), 256, 0, stream>>>(
            hbf, wqkvT + (size_t)l*1536*512, qkvb, nullptr, nullptr,
            2048, 1536, 512, 512, 512, 1536);
        transpose_v<<<dim3(8,8,4), 256, 0, stream>>>(qkvb, vt);
        // T2 = q@posT (+Dtab), T3 = k@posT   (bf16 out)
        gemm_bt<1,4><<<dim3(8,16,64), 256, 0, stream>>>(
            qkvb, posb, t23, nullptr, dtab + (size_t)l*NH*S2,
            512, 1024, 64, 1536, 64, 1024);
        scores_kernel<<<dim3(8,8,4), 256, 0, stream>>>(qkvb, t23, r_r + (size_t)l*NH*64, pmat);
        // o = P @ V
        gemm_bt<2,0><<<dim3(8,1,32), 256, 0, stream>>>(
            pmat, vt, obuf, nullptr, nullptr,
            512, 64, 512, 512, 512, 512);
        const float* hres = (l == 0) ? x : hbuf;
        ln_kernel<<<2048, 64, 0, stream>>>(obuf, hres, ln1g + l*512, ln1b + l*512, h1, h1bf);
        // FFN
        gemm_bt<0,2><<<dim3(32,8,1), 256, 0, stream>>>(
            h1bf, w1T + (size_t)l*512*512, f1bf, b1 + l*512, nullptr,
            2048, 512, 512, 512, 512, 512);
        gemm_bt<0,3><<<dim3(32,8,1), 256, 0, stream>>>(
            f1bf, w2T + (size_t)l*512*512, f2, b2 + l*512, nullptr,
            2048, 512, 512, 512, 512, 512);
        float* outp = (l == NL-1) ? (float*)d_out : hbuf;
        ln_kernel<<<2048, 64, 0, stream>>>(f2, h1, ln2g + l*512, ln2b + l*512, outp, hbf);
    }
}

// Round 5
// 587.731 us; speedup vs baseline: 1.3522x; 1.3522x over previous
//
#include <hip/hip_runtime.h>
#include <math.h>

typedef __attribute__((ext_vector_type(8))) short short8;
typedef __attribute__((ext_vector_type(4))) float f32x4;
typedef short bf16s;   // bf16 stored as raw 16-bit

#define NL 4
#define NB 4
#define SS 512
#define DD 512
#define NH 8
#define S2 1024
#define ROWS 2048   // NB*SS

static __device__ __forceinline__ float bfs2f(short s) {
    union { unsigned u; float f; } c; c.u = ((unsigned)(unsigned short)s) << 16; return c.f;
}
static __device__ __forceinline__ short f2bfs(float f) {
    union { float f; unsigned u; } c; c.f = f;
    unsigned r = 0x7FFFu + ((c.u >> 16) & 1u);
    return (short)((c.u + r) >> 16);
}

// ---------------- prep kernels ----------------

__global__ void pos_kernel(float* __restrict__ posf, bf16s* __restrict__ posb)
{
    const int t = blockIdx.x, f = threadIdx.x;       // 1024 x 32
    float freq = expf((float)f * (-9.210340371976184f / 31.0f));
    float ang  = (float)(t - 512) * freq;
    float sv = sinf(ang), cv = cosf(ang);
    posf[t*64 + f]      = sv;  posf[t*64 + 32 + f] = cv;
    posb[t*64 + f]      = f2bfs(sv);
    posb[t*64 + 32 + f] = f2bfs(cv);
}

__global__ void dtab_kernel(const float* __restrict__ rw, const float* __restrict__ posf,
                            float* __restrict__ dt)
{
    int idx = blockIdx.x*256 + threadIdx.x;          // < NL*NH*1024 = 32768
    int j = idx & 1023, hh = (idx >> 10) & 7, l = idx >> 13;
    const float* rv = rw + (l*NH + hh)*64;
    const float* pv = posf + j*64;
    float s = 0.f;
    #pragma unroll 8
    for (int d = 0; d < 64; ++d) s += rv[d]*pv[d];
    dt[idx] = s;
}

__global__ __launch_bounds__(256) void transpose_cvt(const float* __restrict__ in,
                                                     bf16s* __restrict__ out, int R, int C)
{
    __shared__ float tile[32][33];
    const int bx = blockIdx.x*32, by = blockIdx.y*32;
    const size_t zoff = (size_t)blockIdx.z * R * C;
    in += zoff; out += zoff;
    const int tx = threadIdx.x & 31, ty = threadIdx.x >> 5;
    for (int i = ty; i < 32; i += 8) tile[i][tx] = in[(size_t)(by+i)*C + bx+tx];
    __syncthreads();
    for (int i = ty; i < 32; i += 8) out[(size_t)(bx+i)*R + by+tx] = f2bfs(tile[tx][i]);
}

__global__ void cvt_f2b(const float* __restrict__ in, bf16s* __restrict__ out, int n)
{
    int i = (blockIdx.x*blockDim.x + threadIdx.x)*4;
    if (i >= n) return;
    float4 v = *(const float4*)(in + i);
    out[i]   = f2bfs(v.x); out[i+1] = f2bfs(v.y);
    out[i+2] = f2bfs(v.z); out[i+3] = f2bfs(v.w);
}

// ---------------- generic BT-layout bf16 MFMA GEMM ----------------
// A [M][K] bf16 (lda), B [N][K] bf16 (ldb), C [M][N]
// MODE 0: plain (FFN).     EPI 2: +bias,gelu -> bf16.  EPI 3: +bias -> f32.
// MODE 1: T23 sheared batched (z = (b*8+h)*2+t). writes [m][j+m-512] band, +Dtab for t=0.
// MODE 3: QKV gemm; cols <1024 -> qkvb, cols >=1024 -> transposed into Vt.
template<int MODE, int EPI>
__global__ __launch_bounds__(256) void gemm_bt(
    const bf16s* __restrict__ Abase, const bf16s* __restrict__ Bbase,
    void* __restrict__ Cbase, const float* __restrict__ bias,
    const float* __restrict__ Dtab, bf16s* __restrict__ Vt,
    int M, int N, int K, int lda, int ldb, int ldc)
{
    if constexpr (MODE == 1) {
        int mblk = blockIdx.x*64, nblk = blockIdx.y*64;
        if (mblk + nblk + 126 < 512 || mblk + nblk >= 1024) return;
    }
    const int z = blockIdx.z;
    const bf16s* A = Abase;
    const bf16s* Bp = Bbase;
    float* Cf = (float*)Cbase;
    bf16s* Cb = (bf16s*)Cbase;
    int hIdx = 0, tIdx = 0;
    if constexpr (MODE == 1) {
        int bh = z >> 1; tIdx = z & 1;
        int b_ = bh >> 3; hIdx = bh & 7;
        A  = Abase + (size_t)b_*SS*1536 + hIdx*64 + tIdx*512;
        Cb = (bf16s*)Cbase + (size_t)z*SS*SS;
    }
    const int w = threadIdx.x >> 6, lane = threadIdx.x & 63;
    const int lr = lane & 15, lg = lane >> 4;
    const int m0 = blockIdx.x*64 + (w>>1)*32;
    const int n0 = blockIdx.y*64 + (w&1)*32;
    const int koff = lg*8;
    const bf16s* Arow0 = A + (size_t)(m0 + lr)*lda + koff;
    const bf16s* Arow1 = Arow0 + (size_t)16*lda;
    const bf16s* Brow0 = Bp + (size_t)(n0 + lr)*ldb + koff;
    const bf16s* Brow1 = Brow0 + (size_t)16*ldb;
    f32x4 acc00 = {0,0,0,0}, acc01 = {0,0,0,0}, acc10 = {0,0,0,0}, acc11 = {0,0,0,0};
    for (int k0 = 0; k0 < K; k0 += 32) {
        short8 a0 = *(const short8*)(Arow0 + k0);
        short8 a1 = *(const short8*)(Arow1 + k0);
        short8 b0 = *(const short8*)(Brow0 + k0);
        short8 b1 = *(const short8*)(Brow1 + k0);
        acc00 = __builtin_amdgcn_mfma_f32_16x16x32_bf16(a0, b0, acc00, 0,0,0);
        acc01 = __builtin_amdgcn_mfma_f32_16x16x32_bf16(a0, b1, acc01, 0,0,0);
        acc10 = __builtin_amdgcn_mfma_f32_16x16x32_bf16(a1, b0, acc10, 0,0,0);
        acc11 = __builtin_amdgcn_mfma_f32_16x16x32_bf16(a1, b1, acc11, 0,0,0);
    }
    f32x4 accs[2][2] = {{acc00, acc01},{acc10, acc11}};
    #pragma unroll
    for (int mi = 0; mi < 2; ++mi)
    #pragma unroll
    for (int ni = 0; ni < 2; ++ni) {
        #pragma unroll
        for (int q = 0; q < 4; ++q) {
            int m = m0 + mi*16 + lg*4 + q;
            int c = n0 + ni*16 + lr;
            float val = accs[mi][ni][q];
            if constexpr (MODE == 1) {
                int tt = c + m - 512;           // sheared target col
                if (tt >= 0 && tt < 512) {
                    if (tIdx == 0) val += Dtab[hIdx*S2 + c];
                    Cb[(size_t)m*SS + tt] = f2bfs(val);
                }
            } else if constexpr (MODE == 3) {
                if (c < 1024) {
                    Cb[(size_t)m*1536 + c] = f2bfs(val);
                } else {
                    int d = c - 1024, h = d >> 6, dd = d & 63;
                    int b_ = m >> 9, s = m & 511;
                    Vt[(size_t)((b_*NH + h)*64 + dd)*SS + s] = f2bfs(val);
                }
            } else {
                if constexpr (EPI == 2 || EPI == 3) val += bias[c];
                if constexpr (EPI == 2) val = 0.5f*val*(1.0f + erff(val*0.70710678118f));
                size_t idx = (size_t)m*ldc + c;
                if constexpr (EPI == 3) Cf[idx] = val;
                else Cb[idx] = f2bfs(val);
            }
        }
    }
}

// ---------------- fused scores + rel-pos + softmax + PV ----------------
// block: 128 thr (2 waves), i-tile of 32 rows, one (b,h). grid (16, 8, 4).
// score[r,c] = (q_r+rr)·k_c + T2s[r][c] + M3[c][r];  o = softmax(score/8) @ V
__global__ __launch_bounds__(128) void attn_kernel(
    const bf16s* __restrict__ qkv, const bf16s* __restrict__ t23s,
    const bf16s* __restrict__ vt, const float* __restrict__ rr,
    float* __restrict__ obuf)
{
    __shared__ short smem[32768];           // 64 KB
    short* t2tile = smem;                   // [32][512] swizzled   (reused as P)
    short* band   = smem + 16384;           // [512][32] swizzled
    short* Plds   = smem;

    const int it = blockIdx.x, h = blockIdx.y, b = blockIdx.z;
    const int i0 = it*32;
    const int tid = threadIdx.x;
    const int w = tid >> 6, lane = tid & 63;
    const int lr = lane & 15, lg = lane >> 4;
    const int koff = lg*8;
    const int bh = b*NH + h;

    // ---- stage T2s slice (rows i0..i0+31, 512 cols), 16B-chunk swizzle ----
    {
        const int rl = tid >> 2, e4 = tid & 3;
        const bf16s* src = t23s + ((size_t)(bh*2)*SS + i0 + rl)*SS;
        #pragma unroll
        for (int itc = 0; itc < 16; ++itc) {
            int chunk = itc*4 + e4;
            short8 v = *(const short8*)(src + chunk*8);
            *(short8*)(t2tile + rl*512 + ((chunk ^ (rl & 7))*8)) = v;
        }
        const bf16s* m3b = t23s + ((size_t)(bh*2+1))*SS*SS + i0;
        #pragma unroll
        for (int itc = 0; itc < 16; ++itc) {
            int c = itc*32 + rl;
            short8 v = *(const short8*)(m3b + (size_t)c*SS + e4*8);
            *(short8*)(band + c*32 + ((e4 ^ (c & 3))*8)) = v;
        }
    }

    // ---- q + rr fragments (wave w: rows i0+w*16 .. +15) ----
    short8 aq[2];
    #pragma unroll
    for (int kk = 0; kk < 2; ++kk) {
        const bf16s* pq = qkv + (size_t)(b*SS + i0 + w*16 + lr)*1536 + h*64 + kk*32 + koff;
        short8 raw = *(const short8*)pq;
        #pragma unroll
        for (int j = 0; j < 8; ++j) {
            float f = bfs2f(raw[j]) + rr[h*64 + kk*32 + koff + j];
            raw[j] = f2bfs(f);
        }
        aq[kk] = raw;
    }
    __syncthreads();

    // ---- QK^T ----
    f32x4 acc[32];
    #pragma unroll
    for (int f = 0; f < 32; ++f) acc[f] = (f32x4){0,0,0,0};
    #pragma unroll
    for (int f = 0; f < 32; ++f) {
        const bf16s* pk = qkv + (size_t)(b*SS + f*16 + lr)*1536 + 512 + h*64 + koff;
        short8 b0 = *(const short8*)pk;
        short8 b1 = *(const short8*)(pk + 32);
        acc[f] = __builtin_amdgcn_mfma_f32_16x16x32_bf16(aq[0], b0, acc[f], 0,0,0);
        acc[f] = __builtin_amdgcn_mfma_f32_16x16x32_bf16(aq[1], b1, acc[f], 0,0,0);
    }

    // ---- add T2s + M3 band (LDS), scale ----
    #pragma unroll
    for (int q = 0; q < 4; ++q) {
        const int rl = w*16 + lg*4 + q;
        const int rsw = rl & 7, rc = rl >> 3, r7 = rl & 7;
        #pragma unroll
        for (int f = 0; f < 32; ++f) {
            int c = f*16 + lr;
            float t2 = bfs2f(t2tile[rl*512 + (((c>>3) ^ rsw)*8) + (c&7)]);
            float m3 = bfs2f(band[c*32 + ((rc ^ (c & 3))*8) + r7]);
            acc[f][q] = (acc[f][q] + t2 + m3) * 0.125f;
        }
    }

    // ---- softmax over c (per row r = lg*4+q) ----
    float mx[4] = {-3e38f,-3e38f,-3e38f,-3e38f};
    #pragma unroll
    for (int f = 0; f < 32; ++f)
        #pragma unroll
        for (int q = 0; q < 4; ++q) mx[q] = fmaxf(mx[q], acc[f][q]);
    #pragma unroll
    for (int d = 1; d < 16; d <<= 1)
        #pragma unroll
        for (int q = 0; q < 4; ++q) mx[q] = fmaxf(mx[q], __shfl_xor(mx[q], d));
    float sm[4] = {0,0,0,0};
    #pragma unroll
    for (int f = 0; f < 32; ++f)
        #pragma unroll
        for (int q = 0; q < 4; ++q) {
            float pv = __expf(acc[f][q] - mx[q]);
            acc[f][q] = pv; sm[q] += pv;
        }
    #pragma unroll
    for (int d = 1; d < 16; d <<= 1)
        #pragma unroll
        for (int q = 0; q < 4; ++q) sm[q] += __shfl_xor(sm[q], d);
    float inv[4];
    #pragma unroll
    for (int q = 0; q < 4; ++q) inv[q] = 1.0f / sm[q];

    // ---- P -> LDS (bf16, swizzled), then PV via MFMA ----
    __syncthreads();   // everyone done reading t2tile/band
    #pragma unroll
    for (int q = 0; q < 4; ++q) {
        const int rl = w*16 + lg*4 + q;
        const int rsw = rl & 7;
        #pragma unroll
        for (int f = 0; f < 32; ++f) {
            int c = f*16 + lr;
            Plds[rl*512 + (((c>>3) ^ rsw)*8) + (c&7)] = f2bfs(acc[f][q]*inv[q]);
        }
    }
    __syncthreads();

    const int prow = w*16 + lr, psw = lr & 7;
    #pragma unroll
    for (int dt = 0; dt < 4; ++dt) {
        f32x4 o = {0,0,0,0};
        const bf16s* vrow = vt + ((size_t)(bh*64) + dt*16 + lr)*SS + koff;
        #pragma unroll
        for (int kc = 0; kc < 16; ++kc) {
            short8 pA = *(const short8*)(Plds + prow*512 + (((kc*4 + lg) ^ psw)*8));
            short8 vB = *(const short8*)(vrow + kc*32);
            o = __builtin_amdgcn_mfma_f32_16x16x32_bf16(pA, vB, o, 0,0,0);
        }
        #pragma unroll
        for (int q = 0; q < 4; ++q)
            obuf[(size_t)(b*SS + i0 + w*16 + lg*4 + q)*DD + h*64 + dt*16 + lr] = o[q];
    }
}

// ---------------- layernorm (a + res), writes f32 + bf16 ----------------
__global__ __launch_bounds__(64) void ln_kernel(
    const float* __restrict__ a, const float* __restrict__ res,
    const float* __restrict__ g, const float* __restrict__ be,
    float* __restrict__ outf, bf16s* __restrict__ outb)
{
    const int row = blockIdx.x, lane = threadIdx.x;
    const float4* pa = (const float4*)(a   + (size_t)row*DD) + lane*2;
    const float4* pr = (const float4*)(res + (size_t)row*DD) + lane*2;
    float4 a0 = pa[0], a1 = pa[1], r0 = pr[0], r1 = pr[1];
    float xv[8] = {a0.x+r0.x, a0.y+r0.y, a0.z+r0.z, a0.w+r0.w,
                   a1.x+r1.x, a1.y+r1.y, a1.z+r1.z, a1.w+r1.w};
    float s = 0.f;
    #pragma unroll
    for (int j = 0; j < 8; ++j) s += xv[j];
    #pragma unroll
    for (int d = 1; d < 64; d <<= 1) s += __shfl_xor(s, d);
    float mean = s * (1.0f/512.0f);
    float v = 0.f;
    #pragma unroll
    for (int j = 0; j < 8; ++j) { float t = xv[j]-mean; v += t*t; }
    #pragma unroll
    for (int d = 1; d < 64; d <<= 1) v += __shfl_xor(v, d);
    float rstd = rsqrtf(v*(1.0f/512.0f) + 1e-5f);
    const int c0 = lane*8;
    short8 ob;
    #pragma unroll
    for (int j = 0; j < 8; ++j) {
        float o = (xv[j]-mean)*rstd*g[c0+j] + be[c0+j];
        outf[(size_t)row*DD + c0 + j] = o;
        ob[j] = f2bfs(o);
    }
    *(short8*)(outb + (size_t)row*DD + c0) = ob;
}

// ---------------- host ----------------
extern "C" void kernel_launch(void* const* d_in, const int* in_sizes, int n_in,
                              void* d_out, int out_size, void* d_ws, size_t ws_size,
                              hipStream_t stream)
{
    const float* x    = (const float*)d_in[0];
    const float* Wqkv = (const float*)d_in[1];
    const float* r_r  = (const float*)d_in[2];
    const float* r_w  = (const float*)d_in[3];
    const float* ln1g = (const float*)d_in[4];
    const float* ln1b = (const float*)d_in[5];
    const float* w1   = (const float*)d_in[6];
    const float* b1   = (const float*)d_in[7];
    const float* w2   = (const float*)d_in[8];
    const float* b2   = (const float*)d_in[9];
    const float* ln2g = (const float*)d_in[10];
    const float* ln2b = (const float*)d_in[11];

    char* p = (char*)d_ws;
    auto alloc = [&](size_t bytes) { char* r = p; p += (bytes + 255) & ~(size_t)255; return r; };
    float* posf  = (float*)alloc((size_t)1024*64*4);
    bf16s* posb  = (bf16s*)alloc((size_t)1024*64*2);
    float* dtab  = (float*)alloc((size_t)NL*NH*1024*4);
    bf16s* wqkvT = (bf16s*)alloc((size_t)NL*1536*512*2);
    bf16s* w1T   = (bf16s*)alloc((size_t)NL*512*512*2);
    bf16s* w2T   = (bf16s*)alloc((size_t)NL*512*512*2);
    float* hbuf  = (float*)alloc((size_t)ROWS*512*4);
    bf16s* hbf   = (bf16s*)alloc((size_t)ROWS*512*2);
    bf16s* qkvb  = (bf16s*)alloc((size_t)ROWS*1536*2);
    bf16s* vt    = (bf16s*)alloc((size_t)32*64*512*2);
    bf16s* t23s  = (bf16s*)alloc((size_t)64*512*512*2);
    float* obuf  = (float*)alloc((size_t)ROWS*512*4);
    float* h1    = (float*)alloc((size_t)ROWS*512*4);
    bf16s* h1bf  = (bf16s*)alloc((size_t)ROWS*512*2);
    bf16s* f1bf  = (bf16s*)alloc((size_t)ROWS*512*2);
    float* f2    = (float*)alloc((size_t)ROWS*512*4);

    pos_kernel<<<1024, 32, 0, stream>>>(posf, posb);
    dtab_kernel<<<128, 256, 0, stream>>>(r_w, posf, dtab);
    transpose_cvt<<<dim3(48,16,NL), 256, 0, stream>>>(Wqkv, wqkvT, 512, 1536);
    transpose_cvt<<<dim3(16,16,NL), 256, 0, stream>>>(w1, w1T, 512, 512);
    transpose_cvt<<<dim3(16,16,NL), 256, 0, stream>>>(w2, w2T, 512, 512);
    cvt_f2b<<<1024, 256, 0, stream>>>(x, hbf, ROWS*512);

    for (int l = 0; l < NL; ++l) {
        // qkv = h @ Wqkv  (q,k -> qkvb; v -> Vt transposed)
        gemm_bt<3,1><<<dim3(32,24,1), 256, 0, stream>>>(
            hbf, wqkvT + (size_t)l*1536*512, qkvb, nullptr, nullptr, vt,
            2048, 1536, 512, 512, 512, 1536);
        // T2s (sheared q@posT + Dtab) / M3 (sheared k@posT)
        gemm_bt<1,0><<<dim3(8,16,64), 256, 0, stream>>>(
            qkvb, posb, t23s, nullptr, dtab + (size_t)l*NH*S2, nullptr,
            512, 1024, 64, 1536, 64, 512);
        // fused scores + softmax + PV
        attn_kernel<<<dim3(16,8,4), 128, 0, stream>>>(
            qkvb, t23s, vt, r_r + (size_t)l*NH*64, obuf);
        const float* hres = (l == 0) ? x : hbuf;
        ln_kernel<<<2048, 64, 0, stream>>>(obuf, hres, ln1g + l*512, ln1b + l*512, h1, h1bf);
        // FFN
        gemm_bt<0,2><<<dim3(32,8,1), 256, 0, stream>>>(
            h1bf, w1T + (size_t)l*512*512, f1bf, b1 + l*512, nullptr, nullptr,
            2048, 512, 512, 512, 512, 512);
        gemm_bt<0,3><<<dim3(32,8,1), 256, 0, stream>>>(
            f1bf, w2T + (size_t)l*512*512, f2, b2 + l*512, nullptr, nullptr,
            2048, 512, 512, 512, 512, 512);
        float* outp = (l == NL-1) ? (float*)d_out : hbuf;
        ln_kernel<<<2048, 64, 0, stream>>>(f2, h1, ln2g + l*512, ln2b + l*512, outp, hbf);
    }
}